// Round 9
// baseline (201.101 us; speedup 1.0000x reference)
//
#include <hip/hip_runtime.h>
#include <hip/hip_bf16.h>

#define DIN 128
#define KEIG 4
#define BSH 7
#define BCAP 5120
#define ITEMS 16
#define AVG_D_LOG 3.4965075614664802f
#define BN_EPS 1e-5f

typedef __attribute__((ext_vector_type(8))) short bf16x8;
typedef __attribute__((ext_vector_type(4))) float f32x4;
typedef __attribute__((ext_vector_type(2))) float f32x2;

// float -> bf16 (RNE) raw bits; no NaN inputs in this problem.
static __device__ inline unsigned short f2bf(float f) {
    union { float f; unsigned u; } v; v.f = f;
    unsigned r = v.u + 0x7FFFu + ((v.u >> 16) & 1u);
    return (unsigned short)(r >> 16);
}
static __device__ inline unsigned pack2bf(float lo, float hi) {
    return (unsigned)f2bf(lo) | ((unsigned)f2bf(hi) << 16);
}
static __device__ inline f32x2 up2(unsigned u) {
    f32x2 r;
    r.x = __int_as_float(u << 16);
    r.y = __int_as_float(u & 0xffff0000u);
    return r;
}

// ---------------- prep: h->bf16, W->bf16 transposed, eig0, zero cursors ----------------

__global__ void k_prep(const float* __restrict__ h, unsigned* __restrict__ hb,
                       const float* __restrict__ W, unsigned short* __restrict__ Wt,
                       const float* __restrict__ eig, float* __restrict__ eig0,
                       int* __restrict__ cursor, int* __restrict__ bcur,
                       int nPairs, int wTotal, int N, int nbk)
{
    int i = blockIdx.x * 256 + threadIdx.x;
    if (i < nPairs) {
        float2 v = reinterpret_cast<const float2*>(h)[i];
        hb[i] = pack2bf(v.x, v.y);
    }
    if (i < wTotal) {
        int k = i % 384;
        int rest = i / 384;
        int col = rest & 127;
        int s = rest >> 7;
        Wt[i] = f2bf(W[(s * 384 + k) * 128 + col]);
    }
    if (i < N) {
        eig0[i] = eig[(size_t)i * KEIG];
        cursor[i] = 0;
    }
    if (i < nbk) bcur[i] = 0;
}

// ---------------- pass 1: bucket by dst>>7 with block-bulk reservation ----------------

__global__ void k_bucket(const int* __restrict__ src, const int* __restrict__ dst,
                         const float* __restrict__ eig0, int* __restrict__ bcur,
                         uint2* __restrict__ stag, int E, int nbk)
{
    __shared__ int lcnt[512];
    __shared__ int lbase[512];
    const int t = threadIdx.x;
    for (int b = t; b < nbk; b += 256) lcnt[b] = 0;
    __syncthreads();

    const int e0 = blockIdx.x * (256 * ITEMS);
    int   bky[ITEMS];
    int   rnk[ITEMS];
    uint2 rec[ITEMS];
#pragma unroll
    for (int k = 0; k < ITEMS; ++k) {
        const int e = e0 + t + k * 256;
        if (e < E) {
            const int s = src[e], d = dst[e];
            const float w = fabsf(eig0[s] - eig0[d]);
            rec[k] = make_uint2(((unsigned)f2bf(w) << 16) | (unsigned)s, (unsigned)d);
            bky[k] = d >> BSH;
            rnk[k] = atomicAdd(&lcnt[bky[k]], 1);
        } else bky[k] = -1;
    }
    __syncthreads();
    for (int b = t; b < nbk; b += 256) {
        const int c = lcnt[b];
        lbase[b] = c ? atomicAdd(&bcur[b], c) : 0;
    }
    __syncthreads();
#pragma unroll
    for (int k = 0; k < ITEMS; ++k) {
        if (bky[k] >= 0) {
            const int pos = lbase[bky[k]] + rnk[k];
            if (pos < BCAP) stag[(size_t)bky[k] * BCAP + pos] = rec[k];
        }
    }
}

// ---------------- pass 2: group bucket by dst in LDS; emit packed CSR + offcnt ----------------

__global__ void k_group(const int* __restrict__ bcur, const uint2* __restrict__ stag,
                        unsigned* __restrict__ final_, int2* __restrict__ offcnt, int N)
{
    __shared__ uint2 sst[BCAP];
    __shared__ int hcnt[128];
    __shared__ int sbuf[2][128];
    const int b = blockIdx.x;
    const int t = threadIdx.x;
    const int cb = min(bcur[b], BCAP);

    for (int i = t; i < cb; i += 256) sst[i] = stag[(size_t)b * BCAP + i];
    if (t < 128) hcnt[t] = 0;
    __syncthreads();

    int dl[(BCAP + 255) / 256];
    int rk[(BCAP + 255) / 256];
    int nit = 0;
    for (int i = t; i < cb; i += 256) {
        const int d_loc = sst[i].y & 127;
        dl[nit] = d_loc;
        rk[nit] = atomicAdd(&hcnt[d_loc], 1);
        ++nit;
    }
    __syncthreads();

    // 128-wide inclusive scan (Hillis-Steele), then exclusive
    int cur = 0;
    if (t < 128) sbuf[0][t] = hcnt[t];
    __syncthreads();
    for (int d = 1; d < 128; d <<= 1) {
        if (t < 128) {
            int x = sbuf[cur][t];
            if (t >= d) x += sbuf[cur][t - d];
            sbuf[cur ^ 1][t] = x;
        }
        cur ^= 1;
        __syncthreads();
    }
    const int exb = cur ^ 1;
    if (t < 128) sbuf[exb][t] = sbuf[cur][t] - hcnt[t];   // exclusive
    __syncthreads();

    if (t < 128) {
        const int dg = (b << BSH) + t;
        if (dg < N) offcnt[dg] = make_int2(b * BCAP + sbuf[exb][t], hcnt[t]);
    }
    nit = 0;
    for (int i = t; i < cb; i += 256) {
        final_[(size_t)b * BCAP + sbuf[exb][dl[nit]] + rk[nit]] = sst[i].x;
        ++nit;
    }
}

// ---------------- CSR fallback path (N >= 65536 or small ws) ----------------

__global__ void k_hist(const int* __restrict__ dst, int* __restrict__ counts, int E) {
    int e = blockIdx.x * 256 + threadIdx.x;
    if (e < E) atomicAdd(&counts[dst[e]], 1);
}

__global__ void k_part(const int* __restrict__ counts, int* __restrict__ part, int N) {
    __shared__ int red[4];
    const int t = threadIdx.x;
    const int i = blockIdx.x * 256 + t;
    int v = (i < N) ? counts[i] : 0;
    for (int d = 32; d >= 1; d >>= 1) v += __shfl_down(v, d, 64);
    if ((t & 63) == 0) red[t >> 6] = v;
    __syncthreads();
    if (t == 0) part[blockIdx.x] = red[0] + red[1] + red[2] + red[3];
}

__global__ void k_scan1(const int* __restrict__ part, int* __restrict__ partoff,
                        int* __restrict__ total_out, int NB) {
    __shared__ int buf[2][256];
    const int t = threadIdx.x;
    int v = (t < NB) ? part[t] : 0;
    buf[0][t] = v;
    __syncthreads();
    int cur = 0;
    for (int d = 1; d < 256; d <<= 1) {
        int x = buf[cur][t];
        if (t >= d) x += buf[cur][t - d];
        buf[cur ^ 1][t] = x;
        cur ^= 1;
        __syncthreads();
    }
    if (t < NB) partoff[t] = buf[cur][t] - v;
    if (t == 255) *total_out = buf[cur][255];
}

__global__ void k_off(const int* __restrict__ counts, const int* __restrict__ partoff,
                      int* __restrict__ offsets, int* __restrict__ cursor, int N) {
    __shared__ int buf[2][256];
    const int t = threadIdx.x;
    const int i = blockIdx.x * 256 + t;
    int v = (i < N) ? counts[i] : 0;
    buf[0][t] = v;
    __syncthreads();
    int cur = 0;
    for (int d = 1; d < 256; d <<= 1) {
        int x = buf[cur][t];
        if (t >= d) x += buf[cur][t - d];
        buf[cur ^ 1][t] = x;
        cur ^= 1;
        __syncthreads();
    }
    if (i < N) {
        int excl = partoff[blockIdx.x] + buf[cur][t] - v;
        offsets[i] = excl;
        cursor[i]  = excl;
    }
}

__global__ void k_fill_csr(const int* __restrict__ src, const int* __restrict__ dst,
                           const float* __restrict__ eig0, int* __restrict__ cursor,
                           int2* __restrict__ sedge, int E)
{
    int e = blockIdx.x * 256 + threadIdx.x;
    if (e < E) {
        int s = src[e], d = dst[e];
        float w = fabsf(eig0[s] - eig0[d]);
        int pos = atomicAdd(&cursor[d], 1);
        sedge[pos] = make_int2(s, __float_as_int(w));
    }
}

// ---------------- k_agg: gather + aggregate only (no LDS, no barriers) ----------------
// 256 threads = 16 quarter-waves; each quarter owns ONE node. Per-quarter trip count.
// Register double-buffered 8-edge gather pipeline; writes agg[n][384] bf16 + scal[n].

template<bool PACKED>
__launch_bounds__(256, 4)
__global__ void k_agg(const unsigned* __restrict__ hb,
                      const int2* __restrict__ offcnt, const int* __restrict__ offsets,
                      const unsigned* __restrict__ upk, const int2* __restrict__ sedge,
                      unsigned short* __restrict__ agg, float2* __restrict__ scal, int N)
{
    const int tid = threadIdx.x;
    const int qid = tid >> 4;       // 0..15
    const int l16 = tid & 15;
    const int n = blockIdx.x * 16 + qid;
    if (n >= N) return;

    int e0, cnt;
    if (PACKED) { const int2 oc = offcnt[n]; e0 = oc.x; cnt = oc.y; }
    else        { e0 = offsets[n]; cnt = offsets[n + 1] - e0; }

    const uint4* __restrict__ hb4 = reinterpret_cast<const uint4*>(hb);

    f32x2 s2[4], m2[4], d2[4];
    float wsum = 0.f;
#pragma unroll
    for (int f = 0; f < 4; ++f) {
        s2[f] = (f32x2){0.f, 0.f};
        m2[f] = (f32x2){-INFINITY, -INFINITY};
        d2[f] = (f32x2){0.f, 0.f};
    }
    const int clampi = (cnt > 0) ? cnt - 1 : 0;

    uint4 bufA[8], bufB[8];
    float wvA[8], wvB[8];

#define STAGE(BUF, WV, BASE) do {                                        \
    _Pragma("unroll")                                                    \
    for (int j = 0; j < 8; ++j) {                                        \
        int ci = (BASE) + j; ci = ci < clampi ? ci : clampi;             \
        unsigned sidx;                                                   \
        if (PACKED) {                                                    \
            const unsigned u = upk[e0 + ci];                             \
            WV[j] = __int_as_float(u & 0xffff0000u);                     \
            sidx = (u & 0xffffu) << 4;                                   \
        } else {                                                         \
            const int2 v = sedge[e0 + ci];                               \
            WV[j] = __int_as_float(v.y);                                 \
            sidx = ((unsigned)v.x) << 4;                                 \
        }                                                                \
        BUF[j] = hb4[sidx | (unsigned)l16];                              \
    }                                                                    \
} while (0)

#define ACCUM(BUF, WV, BASE) do {                                        \
    _Pragma("unroll")                                                    \
    for (int j = 0; j < 8; ++j) {                                        \
        if ((BASE) + j < cnt) {                                          \
            const float wj = WV[j];                                      \
            const f32x2 wj2 = (f32x2){wj, wj};                           \
            const f32x2 p0 = up2(BUF[j].x), p1 = up2(BUF[j].y);          \
            const f32x2 p2 = up2(BUF[j].z), p3 = up2(BUF[j].w);          \
            s2[0] += p0; s2[1] += p1; s2[2] += p2; s2[3] += p3;          \
            m2[0].x = fmaxf(m2[0].x, p0.x); m2[0].y = fmaxf(m2[0].y, p0.y); \
            m2[1].x = fmaxf(m2[1].x, p1.x); m2[1].y = fmaxf(m2[1].y, p1.y); \
            m2[2].x = fmaxf(m2[2].x, p2.x); m2[2].y = fmaxf(m2[2].y, p2.y); \
            m2[3].x = fmaxf(m2[3].x, p3.x); m2[3].y = fmaxf(m2[3].y, p3.y); \
            d2[0] += p0 * wj2; d2[1] += p1 * wj2;                        \
            d2[2] += p2 * wj2; d2[3] += p3 * wj2;                        \
            wsum += wj;                                                  \
        }                                                                \
    }                                                                    \
} while (0)

    if (cnt > 0) {
        STAGE(bufA, wvA, 0);
        for (int base = 0; base < cnt; base += 16) {
            const bool haveB = (base + 8) < cnt;
            if (haveB) STAGE(bufB, wvB, base + 8);
            ACCUM(bufA, wvA, base);
            if (base + 16 < cnt) STAGE(bufA, wvA, base + 16);
            if (haveB) ACCUM(bufB, wvB, base + 8);
        }
    }
#undef STAGE
#undef ACCUM

    const float degf = (float)cnt;
    const float inv  = 1.0f / fmaxf(degf, 1.0f);
    const float dinv = 1.0f / (wsum + 1e-30f);
    const bool nz = (cnt > 0);
    uint4 pm, px, pd;
    pm.x = pack2bf(s2[0].x * inv, s2[0].y * inv);
    pm.y = pack2bf(s2[1].x * inv, s2[1].y * inv);
    pm.z = pack2bf(s2[2].x * inv, s2[2].y * inv);
    pm.w = pack2bf(s2[3].x * inv, s2[3].y * inv);
    px.x = pack2bf(nz ? m2[0].x : 0.f, nz ? m2[0].y : 0.f);
    px.y = pack2bf(nz ? m2[1].x : 0.f, nz ? m2[1].y : 0.f);
    px.z = pack2bf(nz ? m2[2].x : 0.f, nz ? m2[2].y : 0.f);
    px.w = pack2bf(nz ? m2[3].x : 0.f, nz ? m2[3].y : 0.f);
    pd.x = pack2bf(d2[0].x * dinv, d2[0].y * dinv);
    pd.y = pack2bf(d2[1].x * dinv, d2[1].y * dinv);
    pd.z = pack2bf(d2[2].x * dinv, d2[2].y * dinv);
    pd.w = pack2bf(d2[3].x * dinv, d2[3].y * dinv);

    uint4* aggv = reinterpret_cast<uint4*>(agg);
    const size_t row = (size_t)n * 48;           // 384 bf16 = 48 uint4
    aggv[row + l16]      = pm;
    aggv[row + 16 + l16] = px;
    aggv[row + 32 + l16] = pd;
    if (l16 == 0) {
        const float logD = logf(degf + 1.0f);
        scal[n] = make_float2(logD / AVG_D_LOG, AVG_D_LOG / fmaxf(logD, 1e-6f));
    }
}

// ---------------- k_mm: MFMA matmul + epilogue (M=32 per block) ----------------

__launch_bounds__(256, 4)
__global__ void k_mm(const unsigned short* __restrict__ agg, const float2* __restrict__ scal,
                     const float* __restrict__ h, const float* __restrict__ snorm,
                     const float* __restrict__ bvec, const float* __restrict__ gam,
                     const float* __restrict__ bet, const float* __restrict__ bmean,
                     const float* __restrict__ bvar, const unsigned short* __restrict__ Wt,
                     float* __restrict__ out, int N)
{
    const int tid  = threadIdx.x;
    const int wave = tid >> 6;
    const int lane = tid & 63;
    const int r16  = lane & 15;
    const int kgrp = lane >> 4;
    const int node0 = blockIdx.x * 32;
    const int cb = wave * 32;

    f32x4 acc[2][2][3];
#pragma unroll
    for (int m = 0; m < 2; ++m)
#pragma unroll
        for (int ct = 0; ct < 2; ++ct)
#pragma unroll
            for (int sv = 0; sv < 3; ++sv)
                acc[m][ct][sv] = (f32x4){0.f, 0.f, 0.f, 0.f};

    for (int ks = 0; ks < 12; ++ks) {
        const int kbase = ks * 32 + kgrp * 8;
        bf16x8 a[2];
#pragma unroll
        for (int m = 0; m < 2; ++m)
            a[m] = *reinterpret_cast<const bf16x8*>(
                &agg[(size_t)(node0 + m * 16 + r16) * 384 + kbase]);
#pragma unroll
        for (int sv = 0; sv < 3; ++sv) {
#pragma unroll
            for (int ct = 0; ct < 2; ++ct) {
                const int col = cb + ct * 16 + r16;
                const bf16x8 b = *reinterpret_cast<const bf16x8*>(
                    &Wt[(size_t)sv * 49152 + (size_t)col * 384 + kbase]);
#pragma unroll
                for (int m = 0; m < 2; ++m)
                    acc[m][ct][sv] = __builtin_amdgcn_mfma_f32_16x16x32_bf16(
                        a[m], b, acc[m][ct][sv], 0, 0, 0);
            }
        }
    }

#pragma unroll
    for (int ct = 0; ct < 2; ++ct) {
        const int col = cb + ct * 16 + r16;
        const float bc  = bvec[col];
        const float mc  = bmean[col];
        const float rs  = rsqrtf(bvar[col] + BN_EPS);
        const float gc  = gam[col];
        const float bec = bet[col];
#pragma unroll
        for (int m = 0; m < 2; ++m) {
#pragma unroll
            for (int r = 0; r < 4; ++r) {
                const int nl = m * 16 + kgrp * 4 + r;
                const int n  = node0 + nl;
                if (n >= N) continue;
                const float2 sc = scal[n];
                float v = acc[m][ct][0][r] + sc.x * acc[m][ct][1][r]
                                           + sc.y * acc[m][ct][2][r];
                float y = (v + bc) * snorm[n];
                y = (y - mc) * rs * gc + bec;
                y = fmaxf(y, 0.f);
                y += h[(size_t)n * DIN + col];
                out[(size_t)n * DIN + col] = y;
            }
        }
    }
}

// ---------------- launch ----------------

extern "C" void kernel_launch(void* const* d_in, const int* in_sizes, int n_in,
                              void* d_out, int out_size, void* d_ws, size_t ws_size,
                              hipStream_t stream)
{
    const float* h     = (const float*)d_in[0];
    const float* eig   = (const float*)d_in[1];
    const float* snorm = (const float*)d_in[2];
    const float* W     = (const float*)d_in[3];
    const float* bvec  = (const float*)d_in[4];
    const float* gam   = (const float*)d_in[5];
    const float* bet   = (const float*)d_in[6];
    const float* bmean = (const float*)d_in[7];
    const float* bvar  = (const float*)d_in[8];
    const int*   esrc  = (const int*)d_in[9];
    const int*   edst  = (const int*)d_in[10];
    float* out = (float*)d_out;

    const int N = in_sizes[0] / DIN;
    const int E = in_sizes[9];
    const int NB = (N + 255) / 256;
    const int nPairs = N * DIN / 2;
    const int wTotal = 3 * 128 * 384;
    const int nbk = (N + 127) >> BSH;
    const int N32 = (N + 31) / 32;
    (void)ws_size; (void)n_in; (void)out_size;

    char* base = (char*)d_ws;
    size_t o = 0;
    auto take = [&](size_t bytes) {
        char* p = base + o;
        o = (o + bytes + 255) & ~(size_t)255;
        return p;
    };
    // common scratch
    unsigned* hb       = (unsigned*)take((size_t)nPairs * 4);
    unsigned short* Wt = (unsigned short*)take((size_t)wTotal * 2);
    float* eig0        = (float*)take((size_t)N * 4);
    int* cursor        = (int*)take((size_t)(N + 1) * 4);
    float2* scal       = (float2*)take((size_t)N * 8);

    const size_t agg_bytes  = (size_t)N32 * 32 * 384 * 2;
    const size_t stag_bytes = (size_t)nbk * BCAP * 8;
    const size_t shared_bytes = agg_bytes > stag_bytes ? agg_bytes : stag_bytes;

    const size_t bucket_bytes = (size_t)nbk * BCAP * 4     // final packed
                              + (size_t)N * 8              // offcnt
                              + (size_t)nbk * 4            // bcur
                              + shared_bytes + 8192;
    const bool bucketOK = (N <= 65536) && (nbk <= 512) && ((o + bucket_bytes) <= ws_size);

    const int gridPrep = (nPairs + 255) / 256;
    const int gridE    = (E + 255) / 256;
    const int gridB    = (E + 256 * ITEMS - 1) / (256 * ITEMS);
    const int gridN16  = (N + 15) / 16;

    if (bucketOK) {
        unsigned* fin   = (unsigned*)take((size_t)nbk * BCAP * 4);
        int2* offcnt    = (int2*)take((size_t)N * 8);
        int* bcur       = (int*)take((size_t)nbk * 4);
        char* shared    = take(shared_bytes);
        uint2* stag     = (uint2*)shared;                 // dead after k_group
        unsigned short* agg = (unsigned short*)shared;    // written by k_agg

        k_prep<<<gridPrep, 256, 0, stream>>>(h, hb, W, Wt, eig, eig0, cursor, bcur,
                                             nPairs, wTotal, N, nbk);
        k_bucket<<<gridB, 256, 0, stream>>>(esrc, edst, eig0, bcur, stag, E, nbk);
        k_group<<<nbk, 256, 0, stream>>>(bcur, stag, fin, offcnt, N);
        k_agg<true><<<gridN16, 256, 0, stream>>>(hb, offcnt, nullptr, fin, nullptr,
                                                 agg, scal, N);
        k_mm<<<N32, 256, 0, stream>>>(agg, scal, h, snorm, bvec, gam, bet, bmean, bvar,
                                      Wt, out, N);
    } else {
        int* counts  = (int*)take((size_t)(N + 1) * 4);
        int* offsets = (int*)take((size_t)(N + 1) * 4);
        int2* sedge  = (int2*)take((size_t)(E + 16) * 8);
        int* part    = (int*)take((size_t)NB * 4);
        int* partoff = (int*)take((size_t)NB * 4);
        int* bcur    = (int*)take(4096);
        unsigned short* agg = (unsigned short*)take(agg_bytes);

        k_prep<<<gridPrep, 256, 0, stream>>>(h, hb, W, Wt, eig, eig0, counts, bcur,
                                             nPairs, wTotal, N, 1);
        k_hist<<<gridE, 256, 0, stream>>>(edst, counts, E);
        k_part<<<NB, 256, 0, stream>>>(counts, part, N);
        k_scan1<<<1, 256, 0, stream>>>(part, partoff, &offsets[N], NB);
        k_off<<<NB, 256, 0, stream>>>(counts, partoff, offsets, cursor, N);
        k_fill_csr<<<gridE, 256, 0, stream>>>(esrc, edst, eig0, cursor, sedge, E);
        k_agg<false><<<gridN16, 256, 0, stream>>>(hb, nullptr, offsets, nullptr, sedge,
                                                  agg, scal, N);
        k_mm<<<N32, 256, 0, stream>>>(agg, scal, h, snorm, bvec, gam, bet, bmean, bvar,
                                      Wt, out, N);
    }
}

// Round 10
// 200.415 us; speedup vs baseline: 1.0034x; 1.0034x over previous
//
#include <hip/hip_runtime.h>
#include <hip/hip_bf16.h>

#define DIN 128
#define KEIG 4
#define BSH 7
#define BCAP 5120
#define ITEMS 16
#define AVG_D_LOG 3.4965075614664802f
#define BN_EPS 1e-5f

typedef __attribute__((ext_vector_type(8))) short bf16x8;
typedef __attribute__((ext_vector_type(4))) float f32x4;
typedef __attribute__((ext_vector_type(2))) float f32x2;

// float -> bf16 (RNE) raw bits; no NaN inputs in this problem.
static __device__ inline unsigned short f2bf(float f) {
    union { float f; unsigned u; } v; v.f = f;
    unsigned r = v.u + 0x7FFFu + ((v.u >> 16) & 1u);
    return (unsigned short)(r >> 16);
}
static __device__ inline unsigned pack2bf(float lo, float hi) {
    return (unsigned)f2bf(lo) | ((unsigned)f2bf(hi) << 16);
}
static __device__ inline f32x2 up2(unsigned u) {
    f32x2 r;
    r.x = __int_as_float(u << 16);
    r.y = __int_as_float(u & 0xffff0000u);
    return r;
}

// ---------------- prep: h->bf16, W->bf16 transposed, eig0, zero cursors ----------------

__global__ void k_prep(const float* __restrict__ h, unsigned* __restrict__ hb,
                       const float* __restrict__ W, unsigned short* __restrict__ Wt,
                       const float* __restrict__ eig, float* __restrict__ eig0,
                       int* __restrict__ cursor, int* __restrict__ bcur,
                       int nPairs, int wTotal, int N, int nbk)
{
    int i = blockIdx.x * 256 + threadIdx.x;
    if (i < nPairs) {
        float2 v = reinterpret_cast<const float2*>(h)[i];
        hb[i] = pack2bf(v.x, v.y);
    }
    if (i < wTotal) {
        int k = i % 384;
        int rest = i / 384;
        int col = rest & 127;
        int s = rest >> 7;
        Wt[i] = f2bf(W[(s * 384 + k) * 128 + col]);
    }
    if (i < N) {
        eig0[i] = eig[(size_t)i * KEIG];
        cursor[i] = 0;
    }
    if (i < nbk) bcur[i] = 0;
}

// ---------------- pass 1: bucket by dst>>7 with block-bulk reservation ----------------

__global__ void k_bucket(const int* __restrict__ src, const int* __restrict__ dst,
                         const float* __restrict__ eig0, int* __restrict__ bcur,
                         uint2* __restrict__ stag, int E, int nbk)
{
    __shared__ int lcnt[512];
    __shared__ int lbase[512];
    const int t = threadIdx.x;
    for (int b = t; b < nbk; b += 256) lcnt[b] = 0;
    __syncthreads();

    const int e0 = blockIdx.x * (256 * ITEMS);
    int   bky[ITEMS];
    int   rnk[ITEMS];
    uint2 rec[ITEMS];
#pragma unroll
    for (int k = 0; k < ITEMS; ++k) {
        const int e = e0 + t + k * 256;
        if (e < E) {
            const int s = src[e], d = dst[e];
            const float w = fabsf(eig0[s] - eig0[d]);
            rec[k] = make_uint2(((unsigned)f2bf(w) << 16) | (unsigned)s, (unsigned)d);
            bky[k] = d >> BSH;
            rnk[k] = atomicAdd(&lcnt[bky[k]], 1);
        } else bky[k] = -1;
    }
    __syncthreads();
    for (int b = t; b < nbk; b += 256) {
        const int c = lcnt[b];
        lbase[b] = c ? atomicAdd(&bcur[b], c) : 0;
    }
    __syncthreads();
#pragma unroll
    for (int k = 0; k < ITEMS; ++k) {
        if (bky[k] >= 0) {
            const int pos = lbase[bky[k]] + rnk[k];
            if (pos < BCAP) stag[(size_t)bky[k] * BCAP + pos] = rec[k];
        }
    }
}

// ---------------- pass 2: group bucket by dst in LDS; emit packed CSR + offcnt ----------------

__global__ void k_group(const int* __restrict__ bcur, const uint2* __restrict__ stag,
                        unsigned* __restrict__ final_, int2* __restrict__ offcnt, int N)
{
    __shared__ uint2 sst[BCAP];
    __shared__ int hcnt[128];
    __shared__ int sbuf[2][128];
    const int b = blockIdx.x;
    const int t = threadIdx.x;
    const int cb = min(bcur[b], BCAP);

    for (int i = t; i < cb; i += 256) sst[i] = stag[(size_t)b * BCAP + i];
    if (t < 128) hcnt[t] = 0;
    __syncthreads();

    int dl[(BCAP + 255) / 256];
    int rk[(BCAP + 255) / 256];
    int nit = 0;
    for (int i = t; i < cb; i += 256) {
        const int d_loc = sst[i].y & 127;
        dl[nit] = d_loc;
        rk[nit] = atomicAdd(&hcnt[d_loc], 1);
        ++nit;
    }
    __syncthreads();

    // 128-wide inclusive scan (Hillis-Steele), then exclusive
    int cur = 0;
    if (t < 128) sbuf[0][t] = hcnt[t];
    __syncthreads();
    for (int d = 1; d < 128; d <<= 1) {
        if (t < 128) {
            int x = sbuf[cur][t];
            if (t >= d) x += sbuf[cur][t - d];
            sbuf[cur ^ 1][t] = x;
        }
        cur ^= 1;
        __syncthreads();
    }
    const int exb = cur ^ 1;
    if (t < 128) sbuf[exb][t] = sbuf[cur][t] - hcnt[t];   // exclusive
    __syncthreads();

    if (t < 128) {
        const int dg = (b << BSH) + t;
        if (dg < N) offcnt[dg] = make_int2(b * BCAP + sbuf[exb][t], hcnt[t]);
    }
    nit = 0;
    for (int i = t; i < cb; i += 256) {
        final_[(size_t)b * BCAP + sbuf[exb][dl[nit]] + rk[nit]] = sst[i].x;
        ++nit;
    }
}

// ---------------- CSR fallback path (N >= 65536 or small ws) ----------------

__global__ void k_hist(const int* __restrict__ dst, int* __restrict__ counts, int E) {
    int e = blockIdx.x * 256 + threadIdx.x;
    if (e < E) atomicAdd(&counts[dst[e]], 1);
}

__global__ void k_part(const int* __restrict__ counts, int* __restrict__ part, int N) {
    __shared__ int red[4];
    const int t = threadIdx.x;
    const int i = blockIdx.x * 256 + t;
    int v = (i < N) ? counts[i] : 0;
    for (int d = 32; d >= 1; d >>= 1) v += __shfl_down(v, d, 64);
    if ((t & 63) == 0) red[t >> 6] = v;
    __syncthreads();
    if (t == 0) part[blockIdx.x] = red[0] + red[1] + red[2] + red[3];
}

__global__ void k_scan1(const int* __restrict__ part, int* __restrict__ partoff,
                        int* __restrict__ total_out, int NB) {
    __shared__ int buf[2][256];
    const int t = threadIdx.x;
    int v = (t < NB) ? part[t] : 0;
    buf[0][t] = v;
    __syncthreads();
    int cur = 0;
    for (int d = 1; d < 256; d <<= 1) {
        int x = buf[cur][t];
        if (t >= d) x += buf[cur][t - d];
        buf[cur ^ 1][t] = x;
        cur ^= 1;
        __syncthreads();
    }
    if (t < NB) partoff[t] = buf[cur][t] - v;
    if (t == 255) *total_out = buf[cur][255];
}

__global__ void k_off(const int* __restrict__ counts, const int* __restrict__ partoff,
                      int* __restrict__ offsets, int* __restrict__ cursor, int N) {
    __shared__ int buf[2][256];
    const int t = threadIdx.x;
    const int i = blockIdx.x * 256 + t;
    int v = (i < N) ? counts[i] : 0;
    buf[0][t] = v;
    __syncthreads();
    int cur = 0;
    for (int d = 1; d < 256; d <<= 1) {
        int x = buf[cur][t];
        if (t >= d) x += buf[cur][t - d];
        buf[cur ^ 1][t] = x;
        cur ^= 1;
        __syncthreads();
    }
    if (i < N) {
        int excl = partoff[blockIdx.x] + buf[cur][t] - v;
        offsets[i] = excl;
        cursor[i]  = excl;
    }
}

__global__ void k_fill_csr(const int* __restrict__ src, const int* __restrict__ dst,
                           const float* __restrict__ eig0, int* __restrict__ cursor,
                           int2* __restrict__ sedge, int E)
{
    int e = blockIdx.x * 256 + threadIdx.x;
    if (e < E) {
        int s = src[e], d = dst[e];
        float w = fabsf(eig0[s] - eig0[d]);
        int pos = atomicAdd(&cursor[d], 1);
        sedge[pos] = make_int2(s, __float_as_int(w));
    }
}

// ---------------- k_agg: gather + aggregate only (no LDS, no barriers) ----------------
// 256 threads = 16 quarter-waves; each quarter owns ONE node. Per-quarter trip count.
// Register double-buffered 8-edge gather pipeline; writes agg[n][384] bf16 + scal[n].

template<bool PACKED>
__launch_bounds__(256, 4)
__global__ void k_agg(const unsigned* __restrict__ hb,
                      const int2* __restrict__ offcnt, const int* __restrict__ offsets,
                      const unsigned* __restrict__ upk, const int2* __restrict__ sedge,
                      unsigned short* __restrict__ agg, float2* __restrict__ scal, int N)
{
    const int tid = threadIdx.x;
    const int qid = tid >> 4;       // 0..15
    const int l16 = tid & 15;
    const int n = blockIdx.x * 16 + qid;
    if (n >= N) return;

    int e0, cnt;
    if (PACKED) { const int2 oc = offcnt[n]; e0 = oc.x; cnt = oc.y; }
    else        { e0 = offsets[n]; cnt = offsets[n + 1] - e0; }

    const uint4* __restrict__ hb4 = reinterpret_cast<const uint4*>(hb);

    f32x2 s2[4], m2[4], d2[4];
    float wsum = 0.f;
#pragma unroll
    for (int f = 0; f < 4; ++f) {
        s2[f] = (f32x2){0.f, 0.f};
        m2[f] = (f32x2){-INFINITY, -INFINITY};
        d2[f] = (f32x2){0.f, 0.f};
    }
    const int clampi = (cnt > 0) ? cnt - 1 : 0;

    uint4 bufA[8], bufB[8];
    float wvA[8], wvB[8];

#define STAGE(BUF, WV, BASE) do {                                        \
    _Pragma("unroll")                                                    \
    for (int j = 0; j < 8; ++j) {                                        \
        int ci = (BASE) + j; ci = ci < clampi ? ci : clampi;             \
        unsigned sidx;                                                   \
        if (PACKED) {                                                    \
            const unsigned u = upk[e0 + ci];                             \
            WV[j] = __int_as_float(u & 0xffff0000u);                     \
            sidx = (u & 0xffffu) << 4;                                   \
        } else {                                                         \
            const int2 v = sedge[e0 + ci];                               \
            WV[j] = __int_as_float(v.y);                                 \
            sidx = ((unsigned)v.x) << 4;                                 \
        }                                                                \
        BUF[j] = hb4[sidx | (unsigned)l16];                              \
    }                                                                    \
} while (0)

#define ACCUM(BUF, WV, BASE) do {                                        \
    _Pragma("unroll")                                                    \
    for (int j = 0; j < 8; ++j) {                                        \
        if ((BASE) + j < cnt) {                                          \
            const float wj = WV[j];                                      \
            const f32x2 wj2 = (f32x2){wj, wj};                           \
            const f32x2 p0 = up2(BUF[j].x), p1 = up2(BUF[j].y);          \
            const f32x2 p2 = up2(BUF[j].z), p3 = up2(BUF[j].w);          \
            s2[0] += p0; s2[1] += p1; s2[2] += p2; s2[3] += p3;          \
            m2[0].x = fmaxf(m2[0].x, p0.x); m2[0].y = fmaxf(m2[0].y, p0.y); \
            m2[1].x = fmaxf(m2[1].x, p1.x); m2[1].y = fmaxf(m2[1].y, p1.y); \
            m2[2].x = fmaxf(m2[2].x, p2.x); m2[2].y = fmaxf(m2[2].y, p2.y); \
            m2[3].x = fmaxf(m2[3].x, p3.x); m2[3].y = fmaxf(m2[3].y, p3.y); \
            d2[0] += p0 * wj2; d2[1] += p1 * wj2;                        \
            d2[2] += p2 * wj2; d2[3] += p3 * wj2;                        \
            wsum += wj;                                                  \
        }                                                                \
    }                                                                    \
} while (0)

    if (cnt > 0) {
        STAGE(bufA, wvA, 0);
        for (int base = 0; base < cnt; base += 16) {
            const bool haveB = (base + 8) < cnt;
            if (haveB) STAGE(bufB, wvB, base + 8);
            ACCUM(bufA, wvA, base);
            if (base + 16 < cnt) STAGE(bufA, wvA, base + 16);
            if (haveB) ACCUM(bufB, wvB, base + 8);
        }
    }
#undef STAGE
#undef ACCUM

    const float degf = (float)cnt;
    const float inv  = 1.0f / fmaxf(degf, 1.0f);
    const float dinv = 1.0f / (wsum + 1e-30f);
    const bool nz = (cnt > 0);
    uint4 pm, px, pd;
    pm.x = pack2bf(s2[0].x * inv, s2[0].y * inv);
    pm.y = pack2bf(s2[1].x * inv, s2[1].y * inv);
    pm.z = pack2bf(s2[2].x * inv, s2[2].y * inv);
    pm.w = pack2bf(s2[3].x * inv, s2[3].y * inv);
    px.x = pack2bf(nz ? m2[0].x : 0.f, nz ? m2[0].y : 0.f);
    px.y = pack2bf(nz ? m2[1].x : 0.f, nz ? m2[1].y : 0.f);
    px.z = pack2bf(nz ? m2[2].x : 0.f, nz ? m2[2].y : 0.f);
    px.w = pack2bf(nz ? m2[3].x : 0.f, nz ? m2[3].y : 0.f);
    pd.x = pack2bf(d2[0].x * dinv, d2[0].y * dinv);
    pd.y = pack2bf(d2[1].x * dinv, d2[1].y * dinv);
    pd.z = pack2bf(d2[2].x * dinv, d2[2].y * dinv);
    pd.w = pack2bf(d2[3].x * dinv, d2[3].y * dinv);

    uint4* aggv = reinterpret_cast<uint4*>(agg);
    const size_t row = (size_t)n * 48;           // 384 bf16 = 48 uint4
    aggv[row + l16]      = pm;
    aggv[row + 16 + l16] = px;
    aggv[row + 32 + l16] = pd;
    if (l16 == 0) {
        const float logD = logf(degf + 1.0f);
        scal[n] = make_float2(logD / AVG_D_LOG, AVG_D_LOG / fmaxf(logD, 1e-6f));
    }
}

// ---------------- k_mm: MFMA matmul + epilogue (M=32 per block) ----------------
// K-loop restructured: batched fragment loads (8 back-to-back global loads, one
// waitcnt) + distance-1 double-buffer so next step's loads hide under MFMAs.

__launch_bounds__(256, 3)
__global__ void k_mm(const unsigned short* __restrict__ agg, const float2* __restrict__ scal,
                     const float* __restrict__ h, const float* __restrict__ snorm,
                     const float* __restrict__ bvec, const float* __restrict__ gam,
                     const float* __restrict__ bet, const float* __restrict__ bmean,
                     const float* __restrict__ bvar, const unsigned short* __restrict__ Wt,
                     float* __restrict__ out, int N)
{
    const int tid  = threadIdx.x;
    const int wave = tid >> 6;
    const int lane = tid & 63;
    const int r16  = lane & 15;
    const int kgrp = lane >> 4;
    const int node0 = blockIdx.x * 32;
    const int cb = wave * 32;

    f32x4 acc[2][2][3];
#pragma unroll
    for (int m = 0; m < 2; ++m)
#pragma unroll
        for (int ct = 0; ct < 2; ++ct)
#pragma unroll
            for (int sv = 0; sv < 3; ++sv)
                acc[m][ct][sv] = (f32x4){0.f, 0.f, 0.f, 0.f};

    const unsigned short* aggb = agg + (size_t)node0 * 384 + kgrp * 8;
    const unsigned short* wtb  = Wt + (size_t)cb * 384 + kgrp * 8;

#define LOADFRAG(A, B, KS) do {                                               \
    const int kb = (KS) * 32;                                                 \
    A[0] = *reinterpret_cast<const bf16x8*>(&aggb[(size_t)r16 * 384 + kb]);   \
    A[1] = *reinterpret_cast<const bf16x8*>(&aggb[(size_t)(16 + r16) * 384 + kb]); \
    _Pragma("unroll")                                                         \
    for (int sv = 0; sv < 3; ++sv)                                            \
        _Pragma("unroll")                                                     \
        for (int ct = 0; ct < 2; ++ct)                                        \
            B[sv * 2 + ct] = *reinterpret_cast<const bf16x8*>(                \
                &wtb[(size_t)sv * 49152 + (size_t)(ct * 16 + r16) * 384 + kb]); \
} while (0)

#define DOMFMA(A, B) do {                                                     \
    _Pragma("unroll")                                                         \
    for (int sv = 0; sv < 3; ++sv)                                            \
        _Pragma("unroll")                                                     \
        for (int ct = 0; ct < 2; ++ct) {                                      \
            acc[0][ct][sv] = __builtin_amdgcn_mfma_f32_16x16x32_bf16(         \
                A[0], B[sv * 2 + ct], acc[0][ct][sv], 0, 0, 0);               \
            acc[1][ct][sv] = __builtin_amdgcn_mfma_f32_16x16x32_bf16(         \
                A[1], B[sv * 2 + ct], acc[1][ct][sv], 0, 0, 0);               \
        }                                                                     \
} while (0)

    bf16x8 aA[2], bA[6], aB[2], bB[6];
    LOADFRAG(aA, bA, 0);
#pragma unroll
    for (int ks = 0; ks < 12; ks += 2) {
        if (ks + 1 < 12) LOADFRAG(aB, bB, ks + 1);
        DOMFMA(aA, bA);
        if (ks + 2 < 12) LOADFRAG(aA, bA, ks + 2);
        if (ks + 1 < 12) DOMFMA(aB, bB);
    }
#undef LOADFRAG
#undef DOMFMA

#pragma unroll
    for (int ct = 0; ct < 2; ++ct) {
        const int col = cb + ct * 16 + r16;
        const float bc  = bvec[col];
        const float mc  = bmean[col];
        const float rs  = rsqrtf(bvar[col] + BN_EPS);
        const float gc  = gam[col];
        const float bec = bet[col];
#pragma unroll
        for (int m = 0; m < 2; ++m) {
#pragma unroll
            for (int r = 0; r < 4; ++r) {
                const int nl = m * 16 + kgrp * 4 + r;
                const int n  = node0 + nl;
                if (n >= N) continue;
                const float2 sc = scal[n];
                float v = acc[m][ct][0][r] + sc.x * acc[m][ct][1][r]
                                           + sc.y * acc[m][ct][2][r];
                float y = (v + bc) * snorm[n];
                y = (y - mc) * rs * gc + bec;
                y = fmaxf(y, 0.f);
                y += h[(size_t)n * DIN + col];
                out[(size_t)n * DIN + col] = y;
            }
        }
    }
}

// ---------------- launch ----------------

extern "C" void kernel_launch(void* const* d_in, const int* in_sizes, int n_in,
                              void* d_out, int out_size, void* d_ws, size_t ws_size,
                              hipStream_t stream)
{
    const float* h     = (const float*)d_in[0];
    const float* eig   = (const float*)d_in[1];
    const float* snorm = (const float*)d_in[2];
    const float* W     = (const float*)d_in[3];
    const float* bvec  = (const float*)d_in[4];
    const float* gam   = (const float*)d_in[5];
    const float* bet   = (const float*)d_in[6];
    const float* bmean = (const float*)d_in[7];
    const float* bvar  = (const float*)d_in[8];
    const int*   esrc  = (const int*)d_in[9];
    const int*   edst  = (const int*)d_in[10];
    float* out = (float*)d_out;

    const int N = in_sizes[0] / DIN;
    const int E = in_sizes[9];
    const int NB = (N + 255) / 256;
    const int nPairs = N * DIN / 2;
    const int wTotal = 3 * 128 * 384;
    const int nbk = (N + 127) >> BSH;
    const int N32 = (N + 31) / 32;
    (void)ws_size; (void)n_in; (void)out_size;

    char* base = (char*)d_ws;
    size_t o = 0;
    auto take = [&](size_t bytes) {
        char* p = base + o;
        o = (o + bytes + 255) & ~(size_t)255;
        return p;
    };
    // common scratch
    unsigned* hb       = (unsigned*)take((size_t)nPairs * 4);
    unsigned short* Wt = (unsigned short*)take((size_t)wTotal * 2);
    float* eig0        = (float*)take((size_t)N * 4);
    int* cursor        = (int*)take((size_t)(N + 1) * 4);
    float2* scal       = (float2*)take((size_t)N * 8);

    const size_t agg_bytes  = (size_t)N32 * 32 * 384 * 2;
    const size_t stag_bytes = (size_t)nbk * BCAP * 8;
    const size_t shared_bytes = agg_bytes > stag_bytes ? agg_bytes : stag_bytes;

    const size_t bucket_bytes = (size_t)nbk * BCAP * 4     // final packed
                              + (size_t)N * 8              // offcnt
                              + (size_t)nbk * 4            // bcur
                              + shared_bytes + 8192;
    const bool bucketOK = (N <= 65536) && (nbk <= 512) && ((o + bucket_bytes) <= ws_size);

    const int gridPrep = (nPairs + 255) / 256;
    const int gridE    = (E + 255) / 256;
    const int gridB    = (E + 256 * ITEMS - 1) / (256 * ITEMS);
    const int gridN16  = (N + 15) / 16;

    if (bucketOK) {
        unsigned* fin   = (unsigned*)take((size_t)nbk * BCAP * 4);
        int2* offcnt    = (int2*)take((size_t)N * 8);
        int* bcur       = (int*)take((size_t)nbk * 4);
        char* shared    = take(shared_bytes);
        uint2* stag     = (uint2*)shared;                 // dead after k_group
        unsigned short* agg = (unsigned short*)shared;    // written by k_agg

        k_prep<<<gridPrep, 256, 0, stream>>>(h, hb, W, Wt, eig, eig0, cursor, bcur,
                                             nPairs, wTotal, N, nbk);
        k_bucket<<<gridB, 256, 0, stream>>>(esrc, edst, eig0, bcur, stag, E, nbk);
        k_group<<<nbk, 256, 0, stream>>>(bcur, stag, fin, offcnt, N);
        k_agg<true><<<gridN16, 256, 0, stream>>>(hb, offcnt, nullptr, fin, nullptr,
                                                 agg, scal, N);
        k_mm<<<N32, 256, 0, stream>>>(agg, scal, h, snorm, bvec, gam, bet, bmean, bvar,
                                      Wt, out, N);
    } else {
        int* counts  = (int*)take((size_t)(N + 1) * 4);
        int* offsets = (int*)take((size_t)(N + 1) * 4);
        int2* sedge  = (int2*)take((size_t)(E + 16) * 8);
        int* part    = (int*)take((size_t)NB * 4);
        int* partoff = (int*)take((size_t)NB * 4);
        int* bcur    = (int*)take(4096);
        unsigned short* agg = (unsigned short*)take(agg_bytes);

        k_prep<<<gridPrep, 256, 0, stream>>>(h, hb, W, Wt, eig, eig0, counts, bcur,
                                             nPairs, wTotal, N, 1);
        k_hist<<<gridE, 256, 0, stream>>>(edst, counts, E);
        k_part<<<NB, 256, 0, stream>>>(counts, part, N);
        k_scan1<<<1, 256, 0, stream>>>(part, partoff, &offsets[N], NB);
        k_off<<<NB, 256, 0, stream>>>(counts, partoff, offsets, cursor, N);
        k_fill_csr<<<gridE, 256, 0, stream>>>(esrc, edst, eig0, cursor, sedge, E);
        k_agg<false><<<gridN16, 256, 0, stream>>>(hb, nullptr, offsets, nullptr, sedge,
                                                  agg, scal, N);
        k_mm<<<N32, 256, 0, stream>>>(agg, scal, h, snorm, bvec, gam, bet, bmean, bvar,
                                      Wt, out, N);
    }
}